// Round 5
// baseline (604.316 us; speedup 1.0000x reference)
//
#include <hip/hip_runtime.h>
#include <math.h>

#define DIMS 160
#define PLANE (DIMS*DIMS)            // 25600
#define NB 2
#define RH 7
#define RL 4
#define KH 15
#define KL 9
#define TS 16
#define NT (DIMS/TS)                 // 10
#define SH 34                        // sXh x-major stride (30 rows + 4): <=2-way banks
#define SL 28                        // sXl x-major stride (24 rows + 4): ~2-way banks
#define CZ 20                        // z outputs per block
#define NCH (DIMS/CZ)                // 8
#define NSTEPS (CZ + 2*RH)           // 34 planes marched per block
#define NBLK (NT*NT*NCH*NB)          // 1600 blocks (~6.25/CU)

struct DoGW { float gl[KL]; float gh[KH]; };

// ---- x-conv of one z-plane's halo rows, direct global -> regs -> LDS ----
// (proven correct & spill-free in R4 pass1; L1/L2 absorb the 2.5x window overlap)
// tid<120: high rows (row=tid>>2, quad=tid&3); 120<=tid<216: low rows.
// x-major LDS layout: all write/read patterns <=2-way bank aliased (free, m136).
__device__ __forceinline__ void xconv_plane(const float* __restrict__ Xb, int zsrc,
                                            int x0, int y0, bool xfast, const DoGW& w,
                                            int tid, float* sXh, float* sXl) {
  const size_t zoff = (size_t)zsrc * PLANE;
  if (tid < 120) {
    const int row = tid >> 2, q = tid & 3;
    const int yg = min(max(y0 + row - RH, 0), DIMS - 1);
    const float* rowp = Xb + zoff + (size_t)yg * DIMS;
    const int xb = x0 + 4 * q - 8;
    float v[20];
    if (xfast) {
      #pragma unroll
      for (int t = 0; t < 5; ++t) *(float4*)&v[4 * t] = *(const float4*)(rowp + xb + 4 * t);
    } else {
      #pragma unroll
      for (int i = 0; i < 20; ++i) v[i] = rowp[min(max(xb + i, 0), DIMS - 1)];
    }
    #pragma unroll
    for (int c = 0; c < 4; ++c) {
      float a = 0.f;
      #pragma unroll
      for (int k = 0; k < KH; ++k) a = fmaf(w.gh[k], v[c + 1 + k], a);
      sXh[(4 * q + c) * SH + row] = a;
    }
  } else if (tid < 216) {
    const int u = tid - 120;
    const int row = u >> 2, q = u & 3;
    const int yg = min(max(y0 + row - RL, 0), DIMS - 1);
    const float* rowp = Xb + zoff + (size_t)yg * DIMS;
    const int xb = x0 + 4 * q - 4;
    float v[12];
    if (xfast) {
      #pragma unroll
      for (int t = 0; t < 3; ++t) *(float4*)&v[4 * t] = *(const float4*)(rowp + xb + 4 * t);
    } else {
      #pragma unroll
      for (int i = 0; i < 12; ++i) v[i] = rowp[min(max(xb + i, 0), DIMS - 1)];
    }
    #pragma unroll
    for (int c = 0; c < 4; ++c) {
      float a = 0.f;
      #pragma unroll
      for (int k = 0; k < KL; ++k) a = fmaf(w.gl[k], v[c + k], a);
      sXl[(4 * q + c) * SL + row] = a;
    }
  }
}

// Fused z-march: per plane: x-conv (global->regs->LDS), ONE barrier,
// y-conv + z accumulator-scatter in regs, retire 1 output/step.
// Double-buffered sX makes 1 barrier/plane safe (write buf @s, read @s after
// barrier; next write to same buf @s+2 is fenced by barrier @s+1).
__global__ __launch_bounds__(256, 6)
void dog_fused2(const float* __restrict__ X, float* __restrict__ out, DoGW w) {
  __shared__ float sXh[2][TS * SH];   // 2*2176 B
  __shared__ float sXl[2][TS * SL];   // 2*1792 B -> 7.9 KB total

  // XCD swizzle: HW round-robins raw bid across 8 XCDs; make logically-adjacent
  // tiles (shared halo rows / planes) land on the same XCD for L2 locality.
  const int raw = blockIdx.x;
  const int bidl = (raw & 7) * (NBLK / 8) + (raw >> 3);
  const int xt = bidl % NT;
  const int yt = (bidl / NT) % NT;
  const int zc = (bidl / (NT * NT)) % NCH;
  const int b  = bidl / (NT * NT * NCH);
  const int x0 = xt * TS, y0 = yt * TS, z0 = zc * CZ;
  const float* Xb = X + (size_t)b * DIMS * PLANE;
  const int tid = threadIdx.x;
  const bool xfast = (x0 >= 8) && (x0 + 24 <= DIMS);
  const int cy = tid >> 4, cx = tid & 15;

  // z accumulator-scatter state (v2-proven):
  // accH[i] @step s holds output zo=z0+s-14+i; plane zp=z0-7+s contributes
  // tap wh[14-i] (all i) and wl[11-i] (i=3..11). accH[0]/accL[0] retire @s>=14.
  float accH[KH], accL[KL + 3];
  #pragma unroll
  for (int i = 0; i < KH; ++i) accH[i] = 0.f;
  #pragma unroll
  for (int i = 0; i < KL + 3; ++i) accL[i] = 0.f;

  for (int s = 0; s < NSTEPS; ++s) {
    const int buf = s & 1;
    const int zsrc = min(max(z0 - RH + s, 0), DIMS - 1);   // replicate z
    xconv_plane(Xb, zsrc, x0, y0, xfast, w, tid, sXh[buf], sXl[buf]);
    __syncthreads();

    float ph = 0.f, pl = 0.f;
    #pragma unroll
    for (int j = 0; j < KH; ++j) ph = fmaf(w.gh[j], sXh[buf][cx * SH + cy + j], ph);
    #pragma unroll
    for (int j = 0; j < KL; ++j) pl = fmaf(w.gl[j], sXl[buf][cx * SL + cy + j], pl);

    #pragma unroll
    for (int i = 0; i < KH; ++i) accH[i] = fmaf(w.gh[KH - 1 - i], ph, accH[i]);
    #pragma unroll
    for (int i = 3; i < KL + 3; ++i) accL[i] = fmaf(w.gl[KL + 2 - i], pl, accL[i]);

    if (s >= 2 * RH) {
      const int zo = z0 + s - 2 * RH;
      out[((size_t)(b * DIMS + zo) * DIMS + (y0 + cy)) * DIMS + (x0 + cx)] = accL[0] - accH[0];
    }
    #pragma unroll
    for (int i = 0; i < KH - 1; ++i) accH[i] = accH[i + 1];
    accH[KH - 1] = 0.f;
    #pragma unroll
    for (int i = 0; i < KL + 2; ++i) accL[i] = accL[i + 1];
    accL[KL + 2] = 0.f;
  }
}

extern "C" void kernel_launch(void* const* d_in, const int* in_sizes, int n_in,
                              void* d_out, int out_size, void* d_ws, size_t ws_size,
                              hipStream_t stream) {
  const float* X = (const float*)d_in[0];
  float* out = (float*)d_out;

  DoGW w;
  {
    double s = 0.0;
    for (int i = 0; i < KL; ++i) {
      double t = i - (KL - 1) / 2.0;
      double g = exp(-(t * t) / (2.0 * 1.0 * 1.0));
      w.gl[i] = (float)g; s += g;
    }
    for (int i = 0; i < KL; ++i) w.gl[i] = (float)((double)w.gl[i] / s);
    s = 0.0;
    for (int i = 0; i < KH; ++i) {
      double t = i - (KH - 1) / 2.0;
      double g = exp(-(t * t) / (2.0 * 1.6 * 1.6));
      w.gh[i] = (float)g; s += g;
    }
    for (int i = 0; i < KH; ++i) w.gh[i] = (float)((double)w.gh[i] / s);
  }

  dog_fused2<<<NBLK, 256, 0, stream>>>(X, out, w);
}

// Round 6
// 167.133 us; speedup vs baseline: 3.6158x; 3.6158x over previous
//
#include <hip/hip_runtime.h>
#include <math.h>

#define DIMS 160
#define PLANE (DIMS*DIMS)          // 25600
#define NB 2
#define RH 7
#define RL 4
#define KH 15
#define KL 9
#define TSX 16
#define TSY 32
#define NTX (DIMS/TSX)             // 10
#define NTY (DIMS/TSY)             // 5
#define CZ 20                      // z outputs per block
#define NCH (DIMS/CZ)              // 8
#define NSTEPS (CZ + 2*RH)         // 34 planes marched
#define YHR (TSY + 2*RH)           // 46 raw halo rows
#define RS 34                      // sRaw row stride (32 data + 2): b64 reads/writes <=2-way
#define SH 49                      // sXh x-major stride (46 rows + 3): yconv b32 reads 1-way/phase
#define SL 41                      // sXl x-major stride (40 rows + 1): 1-way/phase
#define NBLK (NTX*NTY*NCH*NB)      // 800 blocks, 8 waves each

struct DoGW { float gl[KL]; float gh[KH]; };

// z-marching slab, 512 threads, tile 16x32, 1 barrier/plane.
// Per step s: global-load plane s+1 (368 units, float4, coalesced) ->
// xconv plane s from sRaw[cur] (b64 windows) -> sX[cur] -> ds_write loaded
// regs -> sRaw[nxt] -> barrier -> yconv + z accumulator-scatter, retire 1 z.
__global__ __launch_bounds__(512, 4)
void dog_v4(const float* __restrict__ X, float* __restrict__ out, DoGW w) {
  __shared__ float sRaw[2][YHR * RS];       // 2*1564 floats = 12.5 KB
  __shared__ float sXh[2][TSX * SH];        // 2*784 = 6.3 KB
  __shared__ float sXl[2][TSX * SL];        // 2*656 = 5.2 KB  (total ~24 KB)

  const int bid = blockIdx.x;
  const int xt = bid % NTX;
  const int yt = (bid / NTX) % NTY;
  const int zc = (bid / (NTX * NTY)) % NCH;
  const int b  = bid / (NTX * NTY * NCH);
  const int x0 = xt * TSX, y0 = yt * TSY, z0 = zc * CZ;
  const float* Xb = X + (size_t)b * DIMS * PLANE;
  const int tid = threadIdx.x;
  const bool xfast = (x0 >= 8) && (x0 + 24 <= DIMS);

  // loader: 368 units, row=tid>>3 (0..45), q=tid&7; float4 @ raw col 4q (global x0-8+4q)
  const bool l_on = tid < YHR * 8;
  const int lrow = tid >> 3, lq = tid & 7;
  const int lyg = min(max(y0 + lrow - RH, 0), DIMS - 1);
  const int lxb = x0 - 8 + 4 * lq;

  // xconv roles: high 184 units (row 0..45, xq 0..3); low 160 units (row 0..39, xq 0..3)
  const bool xh_on = tid < YHR * 4;
  const int xhr = tid >> 2, xhq = tid & 3;
  const bool xl_on = (tid >= YHR * 4) && (tid < YHR * 4 + (TSY + 2 * RL) * 4);
  const int xlr = (tid - YHR * 4) >> 2, xlq = (tid - YHR * 4) & 3;

  // yconv: all 512 threads, one output column (cx, cy)
  const int cy = tid >> 4, cx = tid & 15;

  auto loadP = [&](int s, float4& v) {
    if (!l_on) return;
    const int zsrc = min(max(z0 - RH + s, 0), DIMS - 1);
    const float* rowp = Xb + ((size_t)zsrc * DIMS + lyg) * DIMS;
    if (xfast) {
      v = *(const float4*)(rowp + lxb);
    } else {
      v.x = rowp[min(max(lxb + 0, 0), DIMS - 1)];
      v.y = rowp[min(max(lxb + 1, 0), DIMS - 1)];
      v.z = rowp[min(max(lxb + 2, 0), DIMS - 1)];
      v.w = rowp[min(max(lxb + 3, 0), DIMS - 1)];
    }
  };
  auto stageP = [&](const float4& v, int buf) {
    if (!l_on) return;
    // two b64 writes (offset even -> 8B aligned); <=2-way per phase
    *(float2*)&sRaw[buf][lrow * RS + 4 * lq]     = make_float2(v.x, v.y);
    *(float2*)&sRaw[buf][lrow * RS + 4 * lq + 2] = make_float2(v.z, v.w);
  };

  float accH[KH], accL[KL + 3];
  #pragma unroll
  for (int i = 0; i < KH; ++i) accH[i] = 0.f;
  #pragma unroll
  for (int i = 0; i < KL + 3; ++i) accL[i] = 0.f;

  // prologue: stage plane 0
  {
    float4 v;
    loadP(0, v);
    stageP(v, 0);
  }
  __syncthreads();

  for (int s = 0; s < NSTEPS; ++s) {
    const int cur = s & 1;
    float4 vnext;
    if (s + 1 < NSTEPS) loadP(s + 1, vnext);   // in flight during xconv

    if (xh_on) {                                // x-conv high: window raw[4xq .. 4xq+20)
      float v[20];
      #pragma unroll
      for (int j = 0; j < 10; ++j)
        *(float2*)&v[2 * j] = *(const float2*)&sRaw[cur][xhr * RS + 4 * xhq + 2 * j];
      #pragma unroll
      for (int c = 0; c < 4; ++c) {
        float a = 0.f;
        #pragma unroll
        for (int k = 0; k < KH; ++k) a = fmaf(w.gh[k], v[c + 1 + k], a);
        sXh[cur][(4 * xhq + c) * SH + xhr] = a;
      }
    }
    if (xl_on) {                                // x-conv low: raw row +3, window +4
      float v[12];
      #pragma unroll
      for (int j = 0; j < 6; ++j)
        *(float2*)&v[2 * j] = *(const float2*)&sRaw[cur][(xlr + 3) * RS + 4 * xlq + 4 + 2 * j];
      #pragma unroll
      for (int c = 0; c < 4; ++c) {
        float a = 0.f;
        #pragma unroll
        for (int k = 0; k < KL; ++k) a = fmaf(w.gl[k], v[c + k], a);
        sXl[cur][(4 * xlq + c) * SL + xlr] = a;
      }
    }
    if (s + 1 < NSTEPS) stageP(vnext, 1 - cur); // waits vmcnt here, after xconv

    __syncthreads();                            // sX[cur] ready; sRaw[nxt] staged

    float ph = 0.f, pl = 0.f;                   // y-conv (1-way LDS reads)
    #pragma unroll
    for (int j = 0; j < KH; ++j) ph = fmaf(w.gh[j], sXh[cur][cx * SH + cy + j], ph);
    #pragma unroll
    for (int j = 0; j < KL; ++j) pl = fmaf(w.gl[j], sXl[cur][cx * SL + cy + j], pl);

    // z accumulator-scatter (v2-proven): slot i holds zo=z0+s-14+i;
    // plane zp=z0-7+s contributes gh[14-i] (all i), gl[11-i] (i=3..11).
    #pragma unroll
    for (int i = 0; i < KH; ++i) accH[i] = fmaf(w.gh[KH - 1 - i], ph, accH[i]);
    #pragma unroll
    for (int i = 3; i < KL + 3; ++i) accL[i] = fmaf(w.gl[KL + 2 - i], pl, accL[i]);

    if (s >= 2 * RH) {
      const int zo = z0 + s - 2 * RH;
      out[((size_t)(b * DIMS + zo) * DIMS + (y0 + cy)) * DIMS + (x0 + cx)] = accL[0] - accH[0];
    }
    #pragma unroll
    for (int i = 0; i < KH - 1; ++i) accH[i] = accH[i + 1];
    accH[KH - 1] = 0.f;
    #pragma unroll
    for (int i = 0; i < KL + 2; ++i) accL[i] = accL[i + 1];
    accL[KL + 2] = 0.f;
  }
}

extern "C" void kernel_launch(void* const* d_in, const int* in_sizes, int n_in,
                              void* d_out, int out_size, void* d_ws, size_t ws_size,
                              hipStream_t stream) {
  const float* X = (const float*)d_in[0];
  float* out = (float*)d_out;

  DoGW w;
  {
    double s = 0.0;
    for (int i = 0; i < KL; ++i) {
      double t = i - (KL - 1) / 2.0;
      double g = exp(-(t * t) / (2.0 * 1.0 * 1.0));
      w.gl[i] = (float)g; s += g;
    }
    for (int i = 0; i < KL; ++i) w.gl[i] = (float)((double)w.gl[i] / s);
    s = 0.0;
    for (int i = 0; i < KH; ++i) {
      double t = i - (KH - 1) / 2.0;
      double g = exp(-(t * t) / (2.0 * 1.6 * 1.6));
      w.gh[i] = (float)g; s += g;
    }
    for (int i = 0; i < KH; ++i) w.gh[i] = (float)((double)w.gh[i] / s);
  }

  dog_v4<<<NBLK, 512, 0, stream>>>(X, out, w);
}

// Round 7
// 159.218 us; speedup vs baseline: 3.7955x; 1.0497x over previous
//
#include <hip/hip_runtime.h>
#include <math.h>

#define DIMS 160
#define PLANE (DIMS*DIMS)          // 25600
#define NB 2
#define RH 7
#define RL 4
#define KH 15
#define KL 9
#define TSX 16
#define TSY 32
#define NTX (DIMS/TSX)             // 10
#define NTY (DIMS/TSY)             // 5
#define CZ 16                      // z outputs per block
#define NCH (DIMS/CZ)              // 10
#define NSTEPS (CZ + 2*RH)         // 30 planes marched
#define YHR (TSY + 2*RH)           // 46 raw halo rows
#define YLR (TSY + 2*RL)           // 40 low halo rows
#define RS 35                      // sRaw stride ODD: window-read start bank (3r+4q)%32 <=2-way
#define SH 49                      // sXh x-major stride (46+3, odd): yconv 1-way/phase
#define SL 41                      // sXl x-major stride (40+1, odd): 1-way/phase
#define NBLK (NTX*NTY*NCH*NB)      // 1000 blocks, 8 waves each (~3.9/CU)

struct DoGW { float gl[KL]; float gh[KH]; };

// z-marching slab, 512 threads, tile 16x32, 1 barrier/plane, double-buffered.
// All sRaw access is scalar float (odd stride breaks 8B align; compiler merges
// adjacent dwords into ds_read2/write2_b32 which are dword-offset safe).
__global__ __launch_bounds__(512, 4)
void dog_v5(const float* __restrict__ X, float* __restrict__ out, DoGW w) {
  __shared__ float sRaw[2][YHR * RS];       // 2*1610 floats = 12.9 KB
  __shared__ float sXh[2][TSX * SH];        // 2*784 = 6.3 KB
  __shared__ float sXl[2][TSX * SL];        // 2*656 = 5.2 KB   (24.4 KB total)

  const int bid = blockIdx.x;
  const int xt = bid % NTX;
  const int yt = (bid / NTX) % NTY;
  const int zc = (bid / (NTX * NTY)) % NCH;
  const int b  = bid / (NTX * NTY * NCH);
  const int x0 = xt * TSX, y0 = yt * TSY, z0 = zc * CZ;
  const float* Xb = X + (size_t)b * DIMS * PLANE;
  const int tid = threadIdx.x;
  const bool xfast = (x0 >= 8) && (x0 + 24 <= DIMS);

  // loader: 368 units (row=tid>>3 0..45, q=tid&7), float4 @ global x0-8+4q
  const bool l_on = tid < YHR * 8;
  const int lrow = tid >> 3, lq = tid & 7;
  const int lyg = min(max(y0 + lrow - RH, 0), DIMS - 1);
  const int lxb = x0 - 8 + 4 * lq;

  // xconv roles: high 184 units; low 160 units (tid 184..343)
  const bool xh_on = tid < YHR * 4;
  const int xhr = tid >> 2, xhq = tid & 3;
  const bool xl_on = (tid >= YHR * 4) && (tid < YHR * 4 + YLR * 4);
  const int xlr = (tid - YHR * 4) >> 2, xlq = (tid - YHR * 4) & 3;

  // yconv: all 512 threads, one output column (cx, cy)
  const int cy = tid >> 4, cx = tid & 15;

  auto loadP = [&](int s, float4& v) {
    if (!l_on) return;
    const int zsrc = min(max(z0 - RH + s, 0), DIMS - 1);
    const float* rowp = Xb + ((size_t)zsrc * DIMS + lyg) * DIMS;
    if (xfast) {
      v = *(const float4*)(rowp + lxb);
    } else {
      v.x = rowp[min(max(lxb + 0, 0), DIMS - 1)];
      v.y = rowp[min(max(lxb + 1, 0), DIMS - 1)];
      v.z = rowp[min(max(lxb + 2, 0), DIMS - 1)];
      v.w = rowp[min(max(lxb + 3, 0), DIMS - 1)];
    }
  };
  auto stageP = [&](const float4& v, int buf) {
    if (!l_on) return;
    float* p = &sRaw[buf][lrow * RS + 4 * lq];   // scalar stores -> ds_write2_b32
    p[0] = v.x; p[1] = v.y; p[2] = v.z; p[3] = v.w;
  };

  float accH[KH], accL[KL + 3];
  #pragma unroll
  for (int i = 0; i < KH; ++i) accH[i] = 0.f;
  #pragma unroll
  for (int i = 0; i < KL + 3; ++i) accL[i] = 0.f;

  {
    float4 v;
    loadP(0, v);
    stageP(v, 0);
  }
  __syncthreads();

  #pragma unroll 2
  for (int s = 0; s < NSTEPS; ++s) {
    const int cur = s & 1;
    float4 vnext;
    if (s + 1 < NSTEPS) loadP(s + 1, vnext);    // global loads in flight over xconv

    if (xh_on) {                                 // x-conv high (K=15), scalar LDS reads
      const float* p = &sRaw[cur][xhr * RS + 4 * xhq];
      float v[20];
      #pragma unroll
      for (int j = 0; j < 20; ++j) v[j] = p[j];  // compiler -> ds_read2_b32, <=2-way
      #pragma unroll
      for (int c = 0; c < 4; ++c) {
        float a = 0.f;
        #pragma unroll
        for (int k = 0; k < KH; ++k) a = fmaf(w.gh[k], v[c + 1 + k], a);
        sXh[cur][(4 * xhq + c) * SH + xhr] = a;
      }
    }
    if (xl_on) {                                 // x-conv low (K=9): raw row +3, col +4
      const float* p = &sRaw[cur][(xlr + 3) * RS + 4 * xlq + 4];
      float v[12];
      #pragma unroll
      for (int j = 0; j < 12; ++j) v[j] = p[j];
      #pragma unroll
      for (int c = 0; c < 4; ++c) {
        float a = 0.f;
        #pragma unroll
        for (int k = 0; k < KL; ++k) a = fmaf(w.gl[k], v[c + k], a);
        sXl[cur][(4 * xlq + c) * SL + xlr] = a;
      }
    }
    if (s + 1 < NSTEPS) stageP(vnext, 1 - cur);  // vmcnt wait lands here

    __syncthreads();                             // sX[cur] ready; sRaw[nxt] staged

    float ph = 0.f, pl = 0.f;                    // y-conv (reads merge to read2)
    #pragma unroll
    for (int j = 0; j < KH; ++j) ph = fmaf(w.gh[j], sXh[cur][cx * SH + cy + j], ph);
    #pragma unroll
    for (int j = 0; j < KL; ++j) pl = fmaf(w.gl[j], sXl[cur][cx * SL + cy + j], pl);

    // z accumulator-scatter: slot i holds zo=z0+s-14+i; plane z0-7+s
    // contributes gh[14-i] (all i), gl[11-i] (i=3..11); slot 0 retires @s>=14.
    #pragma unroll
    for (int i = 0; i < KH; ++i) accH[i] = fmaf(w.gh[KH - 1 - i], ph, accH[i]);
    #pragma unroll
    for (int i = 3; i < KL + 3; ++i) accL[i] = fmaf(w.gl[KL + 2 - i], pl, accL[i]);

    if (s >= 2 * RH) {
      const int zo = z0 + s - 2 * RH;
      out[((size_t)(b * DIMS + zo) * DIMS + (y0 + cy)) * DIMS + (x0 + cx)] = accL[0] - accH[0];
    }
    #pragma unroll
    for (int i = 0; i < KH - 1; ++i) accH[i] = accH[i + 1];
    accH[KH - 1] = 0.f;
    #pragma unroll
    for (int i = 0; i < KL + 2; ++i) accL[i] = accL[i + 1];
    accL[KL + 2] = 0.f;
  }
}

extern "C" void kernel_launch(void* const* d_in, const int* in_sizes, int n_in,
                              void* d_out, int out_size, void* d_ws, size_t ws_size,
                              hipStream_t stream) {
  const float* X = (const float*)d_in[0];
  float* out = (float*)d_out;

  DoGW w;
  {
    double s = 0.0;
    for (int i = 0; i < KL; ++i) {
      double t = i - (KL - 1) / 2.0;
      double g = exp(-(t * t) / (2.0 * 1.0 * 1.0));
      w.gl[i] = (float)g; s += g;
    }
    for (int i = 0; i < KL; ++i) w.gl[i] = (float)((double)w.gl[i] / s);
    s = 0.0;
    for (int i = 0; i < KH; ++i) {
      double t = i - (KH - 1) / 2.0;
      double g = exp(-(t * t) / (2.0 * 1.6 * 1.6));
      w.gh[i] = (float)g; s += g;
    }
    for (int i = 0; i < KH; ++i) w.gh[i] = (float)((double)w.gh[i] / s);
  }

  dog_v5<<<NBLK, 512, 0, stream>>>(X, out, w);
}

// Round 8
// 143.007 us; speedup vs baseline: 4.2258x; 1.1134x over previous
//
#include <hip/hip_runtime.h>
#include <math.h>

#define DIMS 160
#define PLANE (DIMS*DIMS)          // 25600
#define NB 2
#define RH 7
#define RL 4
#define KH 15
#define KL 9
#define TSX 16
#define TSY 32
#define NTX (DIMS/TSX)             // 10
#define NTY (DIMS/TSY)             // 5
#define CZ 16                      // z outputs per block
#define NCH (DIMS/CZ)              // 10
#define NSTEPS (CZ + 2*RH)         // 30 planes marched
#define YHR (TSY + 2*RH)           // 46 raw halo rows
#define YLR (TSY + 2*RL)           // 40 low rows
#define RAWSZ 1860                 // per-buffer sRaw floats (max O = 45*40+17, +32 data)
#define SH 50                      // sXh x-major stride: 2*25 (odd half) -> yconv reads exactly 2-regular
#define SL 42                      // sXl stride: 2*21 -> 2-regular
#define NBLK (NTX*NTY*NCH*NB)      // 1000 blocks

struct DoGW { float gl[KL]; float gh[KH]; };

// sRaw bank swizzle: row r starts at O(r) = 40r + OFF(r&15).
// Row-base bank = 8*((r>>2)&3) + (r&3); then {base + 4q (+j)} over a wave's
// 16 rows x 4 quads hits every bank EXACTLY twice (2-way = free, m136), and
// loader writes {base + 4*q8} over 8 rows x 8 quads are 2-way too.
__device__ __forceinline__ int raw_off(int r) {
  const int x = r & 15;
  return r * 40 + ((8 * ((x >> 2) & 3) + (x & 3) - 8 * (x & 3)) & 31);
}

__global__ __launch_bounds__(512, 4)
void dog_v6(const float* __restrict__ X, float* __restrict__ out, DoGW w) {
  __shared__ float sRaw[2][RAWSZ];          // 2*1860 fl = 14.9 KB
  __shared__ float sXh[2][TSX * SH];        // 2*800  = 6.4 KB
  __shared__ float sXl[2][TSX * SL];        // 2*672  = 5.4 KB  (total 26.6 KB)

  const int bid = blockIdx.x;
  const int xt = bid % NTX;
  const int yt = (bid / NTX) % NTY;
  const int zc = (bid / (NTX * NTY)) % NCH;
  const int b  = bid / (NTX * NTY * NCH);
  const int x0 = xt * TSX, y0 = yt * TSY, z0 = zc * CZ;
  const float* Xb = X + (size_t)b * DIMS * PLANE;
  const int tid = threadIdx.x;
  const bool xfast = (x0 >= 8) && (x0 + 24 <= DIMS);

  // loader: 368 units (row=tid>>3 in 0..45, q8=tid&7), 4 floats @ col 4*q8
  const bool l_on = tid < YHR * 8;
  const int lrow = tid >> 3, lq = tid & 7;
  const int lyg = min(max(y0 + lrow - RH, 0), DIMS - 1);
  const int lxb = x0 - 8 + 4 * lq;
  const int lof = raw_off(lrow) + 4 * lq;

  // merged x-conv: 184 units (row=tid>>2 in 0..45, q=tid&3); one 20-float
  // window serves 4 high outputs and (rows 3..42) 4 low outputs.
  const bool x_on = tid < YHR * 4;
  const int xr = tid >> 2, xq = tid & 3;
  const int xof = raw_off(xr) + 4 * xq;
  const bool xlow = (xr >= 3) && (xr <= 42);

  // y-conv: all 512 threads, one output column (cx, cy)
  const int cy = tid >> 4, cx = tid & 15;

  auto loadP = [&](int s, float4& v) {
    if (!l_on) return;
    const int zsrc = min(max(z0 - RH + s, 0), DIMS - 1);
    const float* rowp = Xb + ((size_t)zsrc * DIMS + lyg) * DIMS;
    if (xfast) {
      v = *(const float4*)(rowp + lxb);
    } else {
      v.x = rowp[min(max(lxb + 0, 0), DIMS - 1)];
      v.y = rowp[min(max(lxb + 1, 0), DIMS - 1)];
      v.z = rowp[min(max(lxb + 2, 0), DIMS - 1)];
      v.w = rowp[min(max(lxb + 3, 0), DIMS - 1)];
    }
  };
  auto stageP = [&](const float4& v, int buf) {
    if (!l_on) return;
    float* p = &sRaw[buf][lof];              // scalar -> ds_write2_b32, 2-way banks
    p[0] = v.x; p[1] = v.y; p[2] = v.z; p[3] = v.w;
  };

  float accH[KH], accL[KL + 3];
  #pragma unroll
  for (int i = 0; i < KH; ++i) accH[i] = 0.f;
  #pragma unroll
  for (int i = 0; i < KL + 3; ++i) accL[i] = 0.f;

  {
    float4 v;
    loadP(0, v);
    stageP(v, 0);
  }
  __syncthreads();

  #pragma unroll 2
  for (int s = 0; s < NSTEPS; ++s) {
    const int cur = s & 1;
    float4 vnext;
    if (s + 1 < NSTEPS) loadP(s + 1, vnext);  // global loads fly over x-conv

    if (x_on) {                                // merged x-conv (2-regular reads)
      const float* p = &sRaw[cur][xof];
      float v[20];
      #pragma unroll
      for (int j = 0; j < 20; ++j) v[j] = p[j];
      #pragma unroll
      for (int c = 0; c < 4; ++c) {            // high, K=15: taps v[c+1..c+15]
        float a = 0.f;
        #pragma unroll
        for (int k = 0; k < KH; ++k) a = fmaf(w.gh[k], v[c + 1 + k], a);
        sXh[cur][(4 * xq + c) * SH + xr] = a;  // {8q+r}-class write: 2-way
      }
      if (xlow) {
        #pragma unroll
        for (int c = 0; c < 4; ++c) {          // low, K=9: taps v[c+4..c+12]
          float a = 0.f;
          #pragma unroll
          for (int k = 0; k < KL; ++k) a = fmaf(w.gl[k], v[c + 4 + k], a);
          sXl[cur][(4 * xq + c) * SL + (xr - 3)] = a;
        }
      }
    }
    if (s + 1 < NSTEPS) stageP(vnext, 1 - cur);

    __syncthreads();                           // sX[cur] ready; sRaw[nxt] staged

    float ph = 0.f, pl = 0.f;                  // y-conv (exactly 2-regular reads)
    #pragma unroll
    for (int j = 0; j < KH; ++j) ph = fmaf(w.gh[j], sXh[cur][cx * SH + cy + j], ph);
    #pragma unroll
    for (int j = 0; j < KL; ++j) pl = fmaf(w.gl[j], sXl[cur][cx * SL + cy + j], pl);

    // z accumulator-scatter: slot i holds zo=z0+s-14+i; plane z0-7+s adds
    // gh[14-i] (all i), gl[11-i] (i=3..11); slot 0 retires @ s>=14.
    #pragma unroll
    for (int i = 0; i < KH; ++i) accH[i] = fmaf(w.gh[KH - 1 - i], ph, accH[i]);
    #pragma unroll
    for (int i = 3; i < KL + 3; ++i) accL[i] = fmaf(w.gl[KL + 2 - i], pl, accL[i]);

    if (s >= 2 * RH) {
      const int zo = z0 + s - 2 * RH;
      out[((size_t)(b * DIMS + zo) * DIMS + (y0 + cy)) * DIMS + (x0 + cx)] = accL[0] - accH[0];
    }
    #pragma unroll
    for (int i = 0; i < KH - 1; ++i) accH[i] = accH[i + 1];
    accH[KH - 1] = 0.f;
    #pragma unroll
    for (int i = 0; i < KL + 2; ++i) accL[i] = accL[i + 1];
    accL[KL + 2] = 0.f;
  }
}

extern "C" void kernel_launch(void* const* d_in, const int* in_sizes, int n_in,
                              void* d_out, int out_size, void* d_ws, size_t ws_size,
                              hipStream_t stream) {
  const float* X = (const float*)d_in[0];
  float* out = (float*)d_out;

  DoGW w;
  {
    double s = 0.0;
    for (int i = 0; i < KL; ++i) {
      double t = i - (KL - 1) / 2.0;
      double g = exp(-(t * t) / (2.0 * 1.0 * 1.0));
      w.gl[i] = (float)g; s += g;
    }
    for (int i = 0; i < KL; ++i) w.gl[i] = (float)((double)w.gl[i] / s);
    s = 0.0;
    for (int i = 0; i < KH; ++i) {
      double t = i - (KH - 1) / 2.0;
      double g = exp(-(t * t) / (2.0 * 1.6 * 1.6));
      w.gh[i] = (float)g; s += g;
    }
    for (int i = 0; i < KH; ++i) w.gh[i] = (float)((double)w.gh[i] / s);
  }

  dog_v6<<<NBLK, 512, 0, stream>>>(X, out, w);
}

// Round 9
// 134.673 us; speedup vs baseline: 4.4873x; 1.0619x over previous
//
#include <hip/hip_runtime.h>
#include <math.h>

#define DIMS 160
#define PLANE (DIMS*DIMS)          // 25600
#define NB 2
#define RH 7
#define RL 4
#define KH 15
#define KL 9
#define TSX 16
#define TSY 32
#define NTX (DIMS/TSX)             // 10
#define NTY (DIMS/TSY)             // 5
#define CZ 16                      // z outputs per block
#define NCH (DIMS/CZ)              // 10
#define NSTEPS (CZ + 2*RH)         // 30 planes marched
#define YHR (TSY + 2*RH)           // 46 raw halo rows
#define YLR (TSY + 2*RL)           // 40 low rows
#define RAWSZ 1860                 // per-buffer sRaw floats
#define SH 50                      // sXh x-major stride (2*odd): yconv reads exactly 2-regular
#define SL 42                      // sXl stride (2*odd): 2-regular
#define NBLK (NTX*NTY*NCH*NB)      // 1000 blocks

struct DoGW { float gl[KL]; float gh[KH]; };

// sRaw bank swizzle (R8-proven: conflicts 17.9M -> 3.2M): row r at 40r+OFF(r&15),
// row-base bank 8*((r>>2)&3)+(r&3); window reads {base+4q+j} and stage writes
// {base+4q8} are exactly 2-regular per wave (2-way = free, m136).
__device__ __forceinline__ int raw_off(int r) {
  const int x = r & 15;
  return r * 40 + ((8 * ((x >> 2) & 3) + (x & 3) - 8 * (x & 3)) & 31);
}

// Distance-2 pipelined z-march, 512 threads, tile 16x32, 1 barrier/plane.
// Segment s (between B(s) and B(s+1)):
//   stage vH (plane s+1, loaded in segment s-1) -> sRaw[1-cur]
//   issue load plane s+2 -> vH            (in flight a FULL segment)
//   yconv + z-scatter + store for plane s-1  (reads sX[1-cur])
//   xconv plane s: sRaw[cur] -> sX[cur]
//   __syncthreads  (vmcnt drain hits a load that's ~600 cyc old)
__global__ __launch_bounds__(512, 4)
void dog_v7(const float* __restrict__ X, float* __restrict__ out, DoGW w) {
  __shared__ float sRaw[2][RAWSZ];          // 14.9 KB
  __shared__ float sXh[2][TSX * SH];        // 6.4 KB
  __shared__ float sXl[2][TSX * SL];        // 5.4 KB (26.6 KB total)

  const int bid = blockIdx.x;
  const int xt = bid % NTX;
  const int yt = (bid / NTX) % NTY;
  const int zc = (bid / (NTX * NTY)) % NCH;
  const int b  = bid / (NTX * NTY * NCH);
  const int x0 = xt * TSX, y0 = yt * TSY, z0 = zc * CZ;
  const float* Xb = X + (size_t)b * DIMS * PLANE;
  const int tid = threadIdx.x;
  const bool xfast = (x0 >= 8) && (x0 + 24 <= DIMS);

  // loader: 368 units (row 0..45, q8 0..7), 4 floats @ global x0-8+4q8
  const bool l_on = tid < YHR * 8;
  const int lrow = tid >> 3, lq = tid & 7;
  const int lyg = min(max(y0 + lrow - RH, 0), DIMS - 1);
  const int lxb = x0 - 8 + 4 * lq;
  const int lof = raw_off(lrow) + 4 * lq;

  // merged x-conv: 184 units (row 0..45, q 0..3); 20-float window serves
  // 4 high outputs, and 4 low outputs on rows 3..42.
  const bool x_on = tid < YHR * 4;
  const int xr = tid >> 2, xq = tid & 3;
  const int xof = raw_off(xr) + 4 * xq;
  const bool xlow = (xr >= 3) && (xr <= 42);

  // y-conv: all 512 threads, one output column (cx, cy)
  const int cy = tid >> 4, cx = tid & 15;

  auto loadP = [&](int s, float4& v) {
    if (!l_on) return;
    const int zsrc = min(max(z0 - RH + s, 0), DIMS - 1);
    const float* rowp = Xb + ((size_t)zsrc * DIMS + lyg) * DIMS;
    if (xfast) {
      v = *(const float4*)(rowp + lxb);
    } else {
      v.x = rowp[min(max(lxb + 0, 0), DIMS - 1)];
      v.y = rowp[min(max(lxb + 1, 0), DIMS - 1)];
      v.z = rowp[min(max(lxb + 2, 0), DIMS - 1)];
      v.w = rowp[min(max(lxb + 3, 0), DIMS - 1)];
    }
  };
  auto stageP = [&](const float4& v, int buf) {
    if (!l_on) return;
    float* p = &sRaw[buf][lof];              // scalar -> ds_write2_b32, 2-way
    p[0] = v.x; p[1] = v.y; p[2] = v.z; p[3] = v.w;
  };

  float accH[KH], accL[KL + 3];
  #pragma unroll
  for (int i = 0; i < KH; ++i) accH[i] = 0.f;
  #pragma unroll
  for (int i = 0; i < KL + 3; ++i) accL[i] = 0.f;

  // consume plane q: yconv from sX[q&1], z-scatter, retire slot 0 @ q>=14.
  auto consumeQ = [&](int q) {
    const int qb = q & 1;
    float ph = 0.f, pl = 0.f;
    #pragma unroll
    for (int j = 0; j < KH; ++j) ph = fmaf(w.gh[j], sXh[qb][cx * SH + cy + j], ph);
    #pragma unroll
    for (int j = 0; j < KL; ++j) pl = fmaf(w.gl[j], sXl[qb][cx * SL + cy + j], pl);
    #pragma unroll
    for (int i = 0; i < KH; ++i) accH[i] = fmaf(w.gh[KH - 1 - i], ph, accH[i]);
    #pragma unroll
    for (int i = 3; i < KL + 3; ++i) accL[i] = fmaf(w.gl[KL + 2 - i], pl, accL[i]);
    if (q >= 2 * RH) {
      const int zo = z0 + q - 2 * RH;
      out[((size_t)(b * DIMS + zo) * DIMS + (y0 + cy)) * DIMS + (x0 + cx)] = accL[0] - accH[0];
    }
    #pragma unroll
    for (int i = 0; i < KH - 1; ++i) accH[i] = accH[i + 1];
    accH[KH - 1] = 0.f;
    #pragma unroll
    for (int i = 0; i < KL + 2; ++i) accL[i] = accL[i + 1];
    accL[KL + 2] = 0.f;
  };

  auto xconvP = [&](int cur) {
    if (!x_on) return;
    const float* p = &sRaw[cur][xof];
    float v[20];
    #pragma unroll
    for (int j = 0; j < 20; ++j) v[j] = p[j];
    #pragma unroll
    for (int c = 0; c < 4; ++c) {            // high, K=15
      float a = 0.f;
      #pragma unroll
      for (int k = 0; k < KH; ++k) a = fmaf(w.gh[k], v[c + 1 + k], a);
      sXh[cur][(4 * xq + c) * SH + xr] = a;
    }
    if (xlow) {
      #pragma unroll
      for (int c = 0; c < 4; ++c) {          // low, K=9: taps v[c+4..c+12]
        float a = 0.f;
        #pragma unroll
        for (int k = 0; k < KL; ++k) a = fmaf(w.gl[k], v[c + 4 + k], a);
        sXl[cur][(4 * xq + c) * SL + (xr - 3)] = a;
      }
    }
  };

  // prologue: plane 0 staged direct; plane 1 held in vH
  float4 vH;
  {
    float4 v0;
    loadP(0, v0);
    stageP(v0, 0);
    loadP(1, vH);
  }
  __syncthreads();                           // B(0): sRaw[0] ready

  #pragma unroll 2
  for (int s = 0; s < NSTEPS; ++s) {
    const int cur = s & 1;
    if (s + 1 < NSTEPS) stageP(vH, 1 - cur); // plane s+1 (loaded 1 segment ago)
    if (s + 2 < NSTEPS) loadP(s + 2, vH);    // issue now, drain at NEXT barrier
    if (s >= 1) consumeQ(s - 1);             // yconv + scatter + store, lagged 1
    xconvP(cur);                             // plane s -> sX[cur]
    __syncthreads();                         // B(s+1)
  }
  consumeQ(NSTEPS - 1);                      // epilogue: final plane + last store
}

extern "C" void kernel_launch(void* const* d_in, const int* in_sizes, int n_in,
                              void* d_out, int out_size, void* d_ws, size_t ws_size,
                              hipStream_t stream) {
  const float* X = (const float*)d_in[0];
  float* out = (float*)d_out;

  DoGW w;
  {
    double s = 0.0;
    for (int i = 0; i < KL; ++i) {
      double t = i - (KL - 1) / 2.0;
      double g = exp(-(t * t) / (2.0 * 1.0 * 1.0));
      w.gl[i] = (float)g; s += g;
    }
    for (int i = 0; i < KL; ++i) w.gl[i] = (float)((double)w.gl[i] / s);
    s = 0.0;
    for (int i = 0; i < KH; ++i) {
      double t = i - (KH - 1) / 2.0;
      double g = exp(-(t * t) / (2.0 * 1.6 * 1.6));
      w.gh[i] = (float)g; s += g;
    }
    for (int i = 0; i < KH; ++i) w.gh[i] = (float)((double)w.gh[i] / s);
  }

  dog_v7<<<NBLK, 512, 0, stream>>>(X, out, w);
}